// Round 3
// baseline (1756.167 us; speedup 1.0000x reference)
//
#include <hip/hip_runtime.h>
#include <cstddef>
#include <cstdint>

#define BATCH_N 32768
#define OUT_DIM 10

typedef unsigned short u16;
typedef __attribute__((ext_vector_type(8))) short short8;
typedef __attribute__((ext_vector_type(4))) float f32x4;

__device__ __forceinline__ float bf2f(u16 h) {
    return __uint_as_float(((uint32_t)h) << 16);
}
__device__ __forceinline__ u16 f2bf(float v) {
    uint32_t b = __float_as_uint(v);
    b += 0x7FFFu + ((b >> 16) & 1u);
    return (u16)(b >> 16);
}
__device__ __forceinline__ void fsplit(float v, u16& h, u16& l) {
    h = f2bf(v);
    l = f2bf(v - bf2f(h));
}
__device__ __forceinline__ void gld16(const void* g, void* l) {
    __builtin_amdgcn_global_load_lds(
        (const __attribute__((address_space(1))) unsigned int*)g,
        (__attribute__((address_space(3))) unsigned int*)l, 16, 0, 0);
}

// ============================================================================
// Fused layer: A_next = EPI( A[32768][512] @ Wcomb[512][512] )
// A = [v0 ; w] bf16 hi/lo, row-major k-contiguous.
// Wcomb packed B-operand style: Wpk[c][k], c = output column, interleaved:
//   c=2u   -> z0[u] column:  k<256: (I-R)[u,k]    k>=256: -P[k-256,u]
//   c=2u+1 -> z1[u] column:  k<256: P[u,k]        k>=256: M[u,k-256]
// Epilogue: val += cc[c]; even lane (c=2u) holds z0, odd holds z1.
//   t = tanh(z0) passed odd-ward via __shfl_xor(1);
//   A_next[b][u] = z0 ; A_next[b][256+u] = z1 + tanh(z0)  (= w_next)
// bf16x3 split product. BM=128, BN=128, BK=32, 4 waves of 64x64. Grid (256,4).
// ============================================================================
__global__ __launch_bounds__(256, 4)
void layer_fused(const u16* __restrict__ Ah, const u16* __restrict__ Al,
                 const u16* __restrict__ Wh, const u16* __restrict__ Wl,
                 const float* __restrict__ cc,
                 u16* __restrict__ Oh, u16* __restrict__ Ol)
{
    __shared__ u16 lds[16384];   // Ah | Al | Wh | Wl tiles, 4 KB-u16 each
    const int t = threadIdx.x;
    const int wave = t >> 6, lane = t & 63;
    const int b0 = blockIdx.x * 128, c0 = blockIdx.y * 128;

    const u16* gp = (wave == 0) ? Ah : (wave == 1) ? Al : (wave == 2) ? Wh : Wl;
    const int rowbase = (wave < 2) ? b0 : c0;
    u16* lb = &lds[wave * 4096];
    size_t goff[8];
#pragma unroll
    for (int j = 0; j < 8; ++j) {
        int r = rowbase + (j & 1) * 64 + lane;
        goff[j] = (size_t)r * 512 + (size_t)((j >> 1) * 8);
    }

    f32x4 acc[4][4];
#pragma unroll
    for (int a = 0; a < 4; ++a)
#pragma unroll
        for (int b = 0; b < 4; ++b) acc[a][b] = (f32x4){0.f, 0.f, 0.f, 0.f};

    const int wm = wave >> 1, wn = wave & 1;
    const int fl = lane & 15, kq = lane >> 4;

    for (int k0 = 0; k0 < 512; k0 += 32) {
        __syncthreads();
#pragma unroll
        for (int j = 0; j < 8; ++j)
            gld16(gp + goff[j] + k0, lb + j * 512);
        __syncthreads();
        short8 afh[4], aflo[4];
#pragma unroll
        for (int mt = 0; mt < 4; ++mt) {
            const int moff = kq * 1024 + (wm * 64 + mt * 16 + fl) * 8;
            afh[mt]  = *(const short8*)&lds[moff];
            aflo[mt] = *(const short8*)&lds[4096 + moff];
        }
#pragma unroll
        for (int nt = 0; nt < 4; ++nt) {
            const int noff = kq * 1024 + (wn * 64 + nt * 16 + fl) * 8;
            short8 bfh = *(const short8*)&lds[8192 + noff];
            short8 bfl = *(const short8*)&lds[12288 + noff];
#pragma unroll
            for (int mt = 0; mt < 4; ++mt) {
                acc[mt][nt] = __builtin_amdgcn_mfma_f32_16x16x32_bf16(afh[mt],  bfh, acc[mt][nt], 0, 0, 0);
                acc[mt][nt] = __builtin_amdgcn_mfma_f32_16x16x32_bf16(afh[mt],  bfl, acc[mt][nt], 0, 0, 0);
                acc[mt][nt] = __builtin_amdgcn_mfma_f32_16x16x32_bf16(aflo[mt], bfh, acc[mt][nt], 0, 0, 0);
            }
        }
    }

    float ccv[4];
#pragma unroll
    for (int nt = 0; nt < 4; ++nt) ccv[nt] = cc[c0 + wn * 64 + nt * 16 + fl];
    const int p = fl & 1;           // column parity: 0 -> z0, 1 -> z1
#pragma unroll
    for (int mt = 0; mt < 4; ++mt) {
#pragma unroll
        for (int nt = 0; nt < 4; ++nt) {
            const int c = c0 + wn * 64 + nt * 16 + fl;
            const int u = c >> 1;
            const int brow = b0 + wm * 64 + mt * 16 + kq * 4;
#pragma unroll
            for (int r = 0; r < 4; ++r) {
                float val = acc[mt][nt][r] + ccv[nt];
                float tv = tanhf(val);
                float tp = __shfl_xor(tv, 1);
                float outv = p ? (val + tp) : val;
                const size_t addr = (size_t)(brow + r) * 512 + p * 256 + u;
                u16 h, l; fsplit(outv, h, l);
                Oh[addr] = h; Ol[addr] = l;
            }
        }
    }
}

// ============================================================================
// Input GEMM: v0[b][u] = x[b][:784] @ W_in + b_in. Writes state
// A[b][u] = v0, A[b][256+u] = 2*tanh(v0)  (w = v1 + tanh(v0), v1 = tanh(v0)).
// ============================================================================
__global__ __launch_bounds__(256, 2)
void gemm_mfma_input(const float* __restrict__ X,
                     const u16* __restrict__ Wh, const u16* __restrict__ Wl,
                     const float* __restrict__ bias,
                     u16* __restrict__ Oh, u16* __restrict__ Ol)
{
    __shared__ u16 lds[16384];
    const int t = threadIdx.x;
    const int wave = t >> 6, lane = t & 63;
    const int b0 = blockIdx.x * 128, u0 = blockIdx.y * 128;

    const u16* gp = (wave < 2) ? Wh : Wl;
    u16* lbB = &lds[(wave < 2) ? 8192 : 12288];
    size_t goffB[4];
#pragma unroll
    for (int i = 0; i < 4; ++i) {
        int j = (wave & 1) * 4 + i;
        int r = u0 + (j & 1) * 64 + lane;
        goffB[i] = (size_t)r * 800 + (size_t)((j >> 1) * 8);
    }
    const int am = t & 127, akh = t >> 7;
    const size_t arow = (size_t)(b0 + am) * 784;

    f32x4 acc[4][4];
#pragma unroll
    for (int a = 0; a < 4; ++a)
#pragma unroll
        for (int b = 0; b < 4; ++b) acc[a][b] = (f32x4){0.f, 0.f, 0.f, 0.f};

    const int wm = wave >> 1, wn = wave & 1;
    const int fl = lane & 15, kq = lane >> 4;

    for (int k0 = 0; k0 < 800; k0 += 32) {
        __syncthreads();
#pragma unroll
        for (int i = 0; i < 4; ++i)
            gld16(gp + goffB[i] + k0, lbB + ((wave & 1) * 4 + i) * 512);
#pragma unroll
        for (int c = 0; c < 4; ++c) {
            const int gk = k0 + akh * 16 + c * 4;
            float4 v = *(const float4*)(X + arow + (gk < 784 ? gk : 0));
            u16 hs0, ls0, hs1, ls1, hs2, ls2, hs3, ls3;
            fsplit(v.x, hs0, ls0); fsplit(v.y, hs1, ls1);
            fsplit(v.z, hs2, ls2); fsplit(v.w, hs3, ls3);
            const int kl = akh * 16 + c * 4;
            const int off = (kl >> 3) * 1024 + am * 8 + (kl & 7);
            ushort4 hv; hv.x = hs0; hv.y = hs1; hv.z = hs2; hv.w = hs3;
            ushort4 lv; lv.x = ls0; lv.y = ls1; lv.z = ls2; lv.w = ls3;
            *(ushort4*)&lds[off] = hv;
            *(ushort4*)&lds[4096 + off] = lv;
        }
        __syncthreads();
        short8 afh[4], aflo[4];
#pragma unroll
        for (int mt = 0; mt < 4; ++mt) {
            const int moff = kq * 1024 + (wm * 64 + mt * 16 + fl) * 8;
            afh[mt]  = *(const short8*)&lds[moff];
            aflo[mt] = *(const short8*)&lds[4096 + moff];
        }
#pragma unroll
        for (int nt = 0; nt < 4; ++nt) {
            const int noff = kq * 1024 + (wn * 64 + nt * 16 + fl) * 8;
            short8 bfh = *(const short8*)&lds[8192 + noff];
            short8 bfl = *(const short8*)&lds[12288 + noff];
#pragma unroll
            for (int mt = 0; mt < 4; ++mt) {
                acc[mt][nt] = __builtin_amdgcn_mfma_f32_16x16x32_bf16(afh[mt],  bfh, acc[mt][nt], 0, 0, 0);
                acc[mt][nt] = __builtin_amdgcn_mfma_f32_16x16x32_bf16(afh[mt],  bfl, acc[mt][nt], 0, 0, 0);
                acc[mt][nt] = __builtin_amdgcn_mfma_f32_16x16x32_bf16(aflo[mt], bfh, acc[mt][nt], 0, 0, 0);
            }
        }
    }

#pragma unroll
    for (int mt = 0; mt < 4; ++mt) {
#pragma unroll
        for (int nt = 0; nt < 4; ++nt) {
            const int u = u0 + wn * 64 + nt * 16 + fl;
            const int brow = b0 + wm * 64 + mt * 16 + kq * 4;
            const float bu = bias[u];
#pragma unroll
            for (int r = 0; r < 4; ++r) {
                const size_t a0 = (size_t)(brow + r) * 512 + u;
                float v0 = acc[mt][nt][r] + bu;
                float w  = 2.f * tanhf(v0);
                u16 h, l;
                fsplit(v0, h, l); Oh[a0] = h;       Ol[a0] = l;
                fsplit(w,  h, l); Oh[a0 + 256] = h; Ol[a0 + 256] = l;
            }
        }
    }
}

// ============================================================================
// fp32 prep (small 256x256 batched work): D[u,v] = EPI(sum_k A[k][u]*B[k][v])
// ============================================================================
template<int EPI>
__launch_bounds__(256)
__global__ void gemm256b(float* __restrict__ D, const float* __restrict__ A,
                         const float* __restrict__ Bm, const float* __restrict__ E)
{
    __shared__ float As[16][64];
    __shared__ float Bs[16][64];
    const int i = blockIdx.z;
    const size_t off = (size_t)i * 65536;
    const float* Ai = A + off;
    const float* Bi = Bm + off;
    const int t  = threadIdx.x;
    const int tx = t & 15, ty = t >> 4;
    const int u0 = blockIdx.y * 64, v0 = blockIdx.x * 64;
    const int lk = t >> 4, lv = (t & 15) << 2;

    float acc[4][4];
#pragma unroll
    for (int m = 0; m < 4; ++m)
#pragma unroll
        for (int n = 0; n < 4; ++n) acc[m][n] = 0.f;

    for (int k0 = 0; k0 < 256; k0 += 16) {
        __syncthreads();
        *(float4*)&As[lk][lv] = *(const float4*)(Ai + (size_t)(k0 + lk) * 256 + u0 + lv);
        *(float4*)&Bs[lk][lv] = *(const float4*)(Bi + (size_t)(k0 + lk) * 256 + v0 + lv);
        __syncthreads();
#pragma unroll
        for (int kk = 0; kk < 16; ++kk) {
            float af[4], bf[4];
            *(float4*)&af[0] = *(const float4*)&As[kk][ty * 4];
            *(float4*)&bf[0] = *(const float4*)&Bs[kk][tx * 4];
#pragma unroll
            for (int m = 0; m < 4; ++m)
#pragma unroll
                for (int n = 0; n < 4; ++n) acc[m][n] += af[m] * bf[n];
        }
    }

#pragma unroll
    for (int m = 0; m < 4; ++m) {
        const int u = u0 + ty * 4 + m;
        const size_t idx = off + (size_t)u * 256 + v0 + tx * 4;
        float4 r; float* rf = &r.x;
        if (EPI == 0) {
#pragma unroll
            for (int n = 0; n < 4; ++n) rf[n] = acc[m][n];
        } else if (EPI == 1) {
#pragma unroll
            for (int n = 0; n < 4; ++n)
                rf[n] = acc[m][n] + ((u == v0 + tx * 4 + n) ? 2.f : 0.f);
        } else {
            float4 e = *(const float4*)&E[idx];
            const float* ef = &e.x;
#pragma unroll
            for (int n = 0; n < 4; ++n) rf[n] = 2.f * ef[n] - acc[m][n];
        }
        *(float4*)&D[idx] = r;
    }
}

__launch_bounds__(256)
__global__ void transpose256(const float* __restrict__ src, float* __restrict__ dst)
{
    __shared__ float tl[32][33];
    const int i = blockIdx.z;
    const float* S = src + (size_t)i * 65536;
    float* Dst = dst + (size_t)i * 65536;
    const int u0 = blockIdx.y * 32, k0 = blockIdx.x * 32;
    const int tx = threadIdx.x, ty = threadIdx.y; // 32 x 8
#pragma unroll
    for (int r = 0; r < 32; r += 8) tl[ty + r][tx] = S[(size_t)(u0 + ty + r) * 256 + k0 + tx];
    __syncthreads();
#pragma unroll
    for (int r = 0; r < 32; r += 8) Dst[(size_t)(k0 + ty + r) * 256 + u0 + tx] = tl[tx][ty + r];
}

__launch_bounds__(256)
__global__ void bq_kernel(const float* __restrict__ B0, const float* __restrict__ q,
                          float* __restrict__ bq)
{
    __shared__ float qs[256];
    const int i = blockIdx.x;
    const int u = threadIdx.x;
    qs[u] = q[i * 256 + u];
    __syncthreads();
    float s = 0.f;
    for (int k = 0; k < 256; ++k) s += B0[(size_t)i * 65536 + (size_t)k * 256 + u] * qs[k];
    bq[i * 256 + u] = 0.1f * s;
}

// c1 = M bq (M symmetric); writes odd cc slots
__launch_bounds__(256)
__global__ void cc1_kernel(const float* __restrict__ M, const float* __restrict__ bq,
                           float* __restrict__ c1, float* __restrict__ cc)
{
    __shared__ float vs[256];
    const int i = blockIdx.x;
    const int u = threadIdx.x;
    vs[u] = bq[i * 256 + u];
    __syncthreads();
    float s = 0.f;
    for (int k = 0; k < 256; ++k) s += M[(size_t)i * 65536 + (size_t)k * 256 + u] * vs[k];
    c1[i * 256 + u] = s;
    cc[i * 512 + 2 * u + 1] = s;
}

// c0 = 0.1 q - B c1 ; writes even cc slots (uses Bt so access is coalesced)
__launch_bounds__(256)
__global__ void cc0_kernel(const float* __restrict__ Bt, const float* __restrict__ q,
                           const float* __restrict__ c1, float* __restrict__ cc)
{
    __shared__ float vs[256];
    const int i = blockIdx.x;
    const int u = threadIdx.x;
    vs[u] = c1[i * 256 + u];
    __syncthreads();
    float s = 0.f;
    for (int k = 0; k < 256; ++k) s += Bt[(size_t)i * 65536 + (size_t)k * 256 + u] * vs[k];
    cc[i * 512 + 2 * u] = 0.1f * q[i * 256 + u] - s;
}

__launch_bounds__(256)
__global__ void alpha_kernel(const float* __restrict__ C, float* __restrict__ alpha)
{
    __shared__ float red[256];
    const int i = blockIdx.x;
    const int u = threadIdx.x;
    float s = 0.f;
    for (int v = 0; v < 256; ++v) s += fabsf(C[(size_t)i * 65536 + (size_t)v * 256 + u]);
    red[u] = s;
    __syncthreads();
    for (int off = 128; off > 0; off >>= 1) {
        if (u < off) red[u] = fmaxf(red[u], red[u + off]);
        __syncthreads();
    }
    if (u == 0) alpha[i] = red[0];
}

__launch_bounds__(256)
__global__ void init_X(float* __restrict__ X, const float* __restrict__ alpha)
{
    const int i = blockIdx.y;
    const float beta = 2.f / (2.f + alpha[i]);
    const int idx4 = (blockIdx.x * 256 + threadIdx.x) * 4;
    const int u = idx4 >> 8;
    const int v = idx4 & 255;
    float4 r;
    r.x = (v     == u) ? beta : 0.f;
    r.y = (v + 1 == u) ? beta : 0.f;
    r.z = (v + 2 == u) ? beta : 0.f;
    r.w = (v + 3 == u) ? beta : 0.f;
    *(float4*)&X[(size_t)i * 65536 + idx4] = r;
}

// Build Wcomb pack: Wpk[i][c][k] hi/lo per the layer_fused layout comment.
__launch_bounds__(256)
__global__ void pack_wcomb(const float* __restrict__ P, const float* __restrict__ R,
                           const float* __restrict__ M,
                           u16* __restrict__ Wh, u16* __restrict__ Wl)
{
    const int i = blockIdx.y;
    const int e = blockIdx.x * 256 + threadIdx.x;   // 0..262143
    const int c = e >> 9, k = e & 511;
    const int u = c >> 1, parity = c & 1;
    const size_t off = (size_t)i * 65536;
    float v;
    if (parity == 0) {
        if (k < 256) v = ((u == k) ? 1.f : 0.f) - R[off + (size_t)u * 256 + k];
        else         v = -P[off + (size_t)(k - 256) * 256 + u];
    } else {
        if (k < 256) v = P[off + (size_t)u * 256 + k];
        else         v = M[off + (size_t)u * 256 + (k - 256)];
    }
    u16 h, l; fsplit(v, h, l);
    const size_t o = (size_t)i * 262144 + (size_t)c * 512 + k;
    Wh[o] = h; Wl[o] = l;
}

// W_in [784][256] -> Wpack [256 u][800 k] (transposed, zero-padded), bf16 hi/lo
__global__ void pack_win(const float* __restrict__ Wi, u16* __restrict__ h, u16* __restrict__ l)
{
    int k = blockIdx.x * 256 + threadIdx.x;
    int u = blockIdx.y;
    if (k >= 800) return;
    float v = (k < 784) ? Wi[(size_t)k * 256 + u] : 0.f;
    u16 hh, ll; fsplit(v, hh, ll);
    h[(size_t)u * 800 + k] = hh;
    l[(size_t)u * 800 + k] = ll;
}

// out[b,o] = sum_u A[b][u] * W_out[u][o] + b_out[o]   (A stride 512, first half = v0)
__launch_bounds__(256)
__global__ void out_kernel(const u16* __restrict__ V0h, const u16* __restrict__ V0l,
                           const float* __restrict__ Wo, const float* __restrict__ bo,
                           float* __restrict__ out)
{
    __shared__ float Wl_s[2560];
    const int t = threadIdx.x;
    for (int i = t; i < 2560; i += 256) Wl_s[i] = Wo[i];
    __syncthreads();
    const int b = blockIdx.x * 256 + t;
    float acc[OUT_DIM];
#pragma unroll
    for (int o = 0; o < OUT_DIM; ++o) acc[o] = bo[o];
    const size_t base = (size_t)b * 512;
    for (int u8 = 0; u8 < 256; u8 += 8) {
        uint4 hv = *(const uint4*)&V0h[base + u8];
        uint4 lv = *(const uint4*)&V0l[base + u8];
        const uint32_t* hw = &hv.x; const uint32_t* lw = &lv.x;
#pragma unroll
        for (int p = 0; p < 4; ++p) {
            float e0 = __uint_as_float(hw[p] << 16) + __uint_as_float(lw[p] << 16);
            float e1 = __uint_as_float(hw[p] & 0xFFFF0000u) + __uint_as_float(lw[p] & 0xFFFF0000u);
            const float* w0 = &Wl_s[(u8 + p * 2) * OUT_DIM];
#pragma unroll
            for (int o = 0; o < OUT_DIM; ++o) acc[o] += e0 * w0[o] + e1 * w0[OUT_DIM + o];
        }
    }
#pragma unroll
    for (int o = 0; o < OUT_DIM; ++o) out[(size_t)b * OUT_DIM + o] = acc[o];
}

extern "C" void kernel_launch(void* const* d_in, const int* in_sizes, int n_in,
                              void* d_out, int out_size, void* d_ws, size_t ws_size,
                              hipStream_t stream)
{
    const float* x     = (const float*)d_in[0];
    const float* W_in  = (const float*)d_in[1];
    const float* b_in  = (const float*)d_in[2];
    const float* B0    = (const float*)d_in[3];
    const float* q     = (const float*)d_in[4];
    const float* W_out = (const float*)d_in[5];
    const float* b_out = (const float*)d_in[6];

    const size_t VN512 = (size_t)BATCH_N * 512;   // 16,777,216 elems (32 MB u16)
    u16* U   = (u16*)d_ws;
    u16* A1h = U;
    u16* A1l = U + VN512;
    u16* A2h = U + 2 * VN512;
    u16* A2l = U + 3 * VN512;
    u16* Wch = U + 4 * VN512;            // 8 * 262144
    u16* Wcl = Wch + 8 * 262144;
    u16* Wih = Wcl + 8 * 262144;         // 256*800
    u16* Wil = Wih + 204800;
    float* bq    = (float*)(Wil + 204800);
    float* alpha = bq + 2048;
    float* c1    = alpha + 8;
    float* cc    = c1 + 2048;            // 8*512

    // fp32 prep scratch aliased into A2 (prep completes before layer 0 writes A2)
    float* F  = (float*)A2h;             // 16M floats available
    float* Bt = F;
    float* C  = F + 1 * 524288;
    float* X  = F + 2 * 524288;
    float* X2 = F + 3 * 524288;
    float* Y  = F + 4 * 524288;
    float* P  = F + 5 * 524288;
    float* R  = F + 6 * 524288;

    // ---- per-layer matrix prep (fp32) ----
    transpose256<<<dim3(8, 8, 8), dim3(32, 8), 0, stream>>>(B0, Bt);
    bq_kernel<<<8, 256, 0, stream>>>(B0, q, bq);
    gemm256b<1><<<dim3(4, 4, 8), 256, 0, stream>>>(C, B0, B0, nullptr); // C = B^T B + 2I
    alpha_kernel<<<8, 256, 0, stream>>>(C, alpha);
    init_X<<<dim3(64, 8), 256, 0, stream>>>(X, alpha);
    float* Xc = X; float* Xn = X2;
    for (int it = 0; it < 6; ++it) {   // Newton-Schulz: X <- 2X - X C X
        gemm256b<0><<<dim3(4, 4, 8), 256, 0, stream>>>(Y, C, Xc, nullptr);
        gemm256b<2><<<dim3(4, 4, 8), 256, 0, stream>>>(Xn, Xc, Y, Xc);
        float* tmp = Xc; Xc = Xn; Xn = tmp;
    }
    // Xc = M = (B^T B + 2I)^{-1} (symmetric)
    gemm256b<0><<<dim3(4, 4, 8), 256, 0, stream>>>(P, Xc, Bt, nullptr);  // P = M B^T
    gemm256b<0><<<dim3(4, 4, 8), 256, 0, stream>>>(R, Bt, P, nullptr);   // R = B P
    cc1_kernel<<<8, 256, 0, stream>>>(Xc, bq, c1, cc);                   // c1 = M bq
    cc0_kernel<<<8, 256, 0, stream>>>(Bt, q, c1, cc);                    // c0 = 0.1q - B c1

    // ---- packs ----
    pack_wcomb<<<dim3(1024, 8), 256, 0, stream>>>(P, R, Xc, Wch, Wcl);
    pack_win<<<dim3(4, 256), 256, 0, stream>>>(W_in, Wih, Wil);

    // ---- input layer: A1 = [v0 ; 2 tanh(v0)] ----
    gemm_mfma_input<<<dim3(BATCH_N / 128, 2), 256, 0, stream>>>(
        x, Wih, Wil, b_in, A1h, A1l);

    // ---- 8 fused layers (ping-pong A1 <-> A2) ----
    const u16* sh = A1h; const u16* sl = A1l;
    u16* dh = A2h; u16* dl = A2l;
    for (int i = 0; i < 8; ++i) {
        layer_fused<<<dim3(BATCH_N / 128, 4), 256, 0, stream>>>(
            sh, sl, Wch + (size_t)i * 262144, Wcl + (size_t)i * 262144,
            cc + i * 512, dh, dl);
        const u16* th = sh; const u16* tl_ = sl;
        sh = dh; sl = dl;
        dh = (u16*)th; dl = (u16*)tl_;
    }
    // after 8 layers state is back in A1 (sh/sl)

    // ---- output layer ----
    out_kernel<<<BATCH_N / 256, 256, 0, stream>>>(sh, sl, W_out, b_out, (float*)d_out);
}

// Round 4
// 1130.011 us; speedup vs baseline: 1.5541x; 1.5541x over previous
//
#include <hip/hip_runtime.h>
#include <cstddef>
#include <cstdint>

#define BATCH_N 32768
#define OUT_DIM 10

typedef unsigned short u16;
typedef __attribute__((ext_vector_type(8))) short short8;
typedef __attribute__((ext_vector_type(4))) float f32x4;

__device__ __forceinline__ float bf2f(u16 h) {
    return __uint_as_float(((uint32_t)h) << 16);
}
__device__ __forceinline__ u16 f2bf(float v) {
    uint32_t b = __float_as_uint(v);
    b += 0x7FFFu + ((b >> 16) & 1u);
    return (u16)(b >> 16);
}
__device__ __forceinline__ void fsplit(float v, u16& h, u16& l) {
    h = f2bf(v);
    l = f2bf(v - bf2f(h));
}
__device__ __forceinline__ float tanh_fast(float x) {
    float e = __expf(2.f * x);        // inf -> 1, 0 -> -1 : robust
    return 1.f - 2.f / (e + 1.f);
}

// ============================================================================
// MEGA-FUSED NETWORK KERNEL.
// Each block owns 64 batch rows; the [v0 ; w] state (64 x 512, bf16) lives in
// LDS in MFMA A-fragment layout: state[ks(16)][mt(4)][lane(64)][j(8)], where
// element (m, k): mt=m>>4, ks=k>>5, lane=((k>>3)&3)*16 + (m&15), j=k&7.
// Weights are bf16 hi/lo, B-operand layout Wpk[c][k] (c-major rows of K):
// a lane's fragment = 8 consecutive u16 -> coalesced 1KB/wave global loads,
// served from L2 (weights are shared by all blocks).
// Wcomb columns interleaved: c=2u -> z0[u], c=2u+1 -> z1[u]; epilogue does
// val+=cc[c]; tanh hand-off even->odd lane via shfl_xor(1); state update
// v0[u]=z0 (k=u), w[u]=z1+tanh(z0) (k=256+u). 2 barriers per layer.
// ============================================================================
__global__ __launch_bounds__(256, 2)
void meganet(const float* __restrict__ X,
             const u16* __restrict__ Wih, const u16* __restrict__ Wil,
             const float* __restrict__ b_in,
             const u16* __restrict__ Wch, const u16* __restrict__ Wcl,
             const float* __restrict__ cc,
             const float* __restrict__ Wo, const float* __restrict__ bo,
             float* __restrict__ out)
{
    __shared__ u16 state[32768];     // 64 KB
    __shared__ float aux[2560];      // 10 KB: x-chunk staging, later W_out copy
    const int t = threadIdx.x;
    const int wave = t >> 6, lane = t & 63;
    const int fl = lane & 15, kq = lane >> 4;
    const int b0 = blockIdx.x * 64;

    // ---------------- input stage: v0 = x @ W_in + b_in (K=784, pad 800) ----
    f32x4 ai[4][4];
#pragma unroll
    for (int a = 0; a < 4; ++a)
#pragma unroll
        for (int b = 0; b < 4; ++b) ai[a][b] = (f32x4){0.f, 0.f, 0.f, 0.f};

    u16* xbuf = (u16*)aux;           // 2048 u16 chunk buffer
    const int xr = t >> 2;           // row 0..63
    const int xk = (t & 3) * 8;      // 0,8,16,24
    const size_t xrow = (size_t)(b0 + xr) * 784;

    for (int k0 = 0; k0 < 800; k0 += 32) {
        const int gk = k0 + xk;
        const int ga = (gk <= 776) ? gk : 776;   // clamp; W_in pack is 0 for k>=784
        __syncthreads();
        float4 xa = *(const float4*)(X + xrow + ga);
        float4 xb = *(const float4*)(X + xrow + ga + 4);
        const int off = (xr >> 4) * 512 + ((xk >> 3) * 16 + (xr & 15)) * 8;
        ushort4 ha, hb;
        ha.x = f2bf(xa.x); ha.y = f2bf(xa.y); ha.z = f2bf(xa.z); ha.w = f2bf(xa.w);
        hb.x = f2bf(xb.x); hb.y = f2bf(xb.y); hb.z = f2bf(xb.z); hb.w = f2bf(xb.w);
        *(ushort4*)&xbuf[off] = ha;
        *(ushort4*)&xbuf[off + 4] = hb;
        __syncthreads();
        short8 af[4];
#pragma unroll
        for (int mt = 0; mt < 4; ++mt)
            af[mt] = *(const short8*)&xbuf[mt * 512 + lane * 8];
#pragma unroll
        for (int nt = 0; nt < 4; ++nt) {
            const size_t wo = (size_t)(wave * 64 + nt * 16 + fl) * 800 + k0 + kq * 8;
            short8 bh = *(const short8*)(Wih + wo);
            short8 bl = *(const short8*)(Wil + wo);
#pragma unroll
            for (int mt = 0; mt < 4; ++mt) {
                ai[mt][nt] = __builtin_amdgcn_mfma_f32_16x16x32_bf16(af[mt], bh, ai[mt][nt], 0, 0, 0);
                ai[mt][nt] = __builtin_amdgcn_mfma_f32_16x16x32_bf16(af[mt], bl, ai[mt][nt], 0, 0, 0);
            }
        }
    }
    // input epilogue: write state v0 (k=u), w=2*tanh(v0) (k=256+u)
    {
        float bi[4];
#pragma unroll
        for (int nt = 0; nt < 4; ++nt) bi[nt] = b_in[wave * 64 + nt * 16 + fl];
#pragma unroll
        for (int nt = 0; nt < 4; ++nt) {
            const int u = wave * 64 + nt * 16 + fl;
            const int ks = u >> 5;
            const int cbase = (((u >> 3) & 3) * 16) * 8 + (u & 7);
#pragma unroll
            for (int mt = 0; mt < 4; ++mt) {
#pragma unroll
                for (int r = 0; r < 4; ++r) {
                    float v = ai[mt][nt][r] + bi[nt];
                    float w = 2.f * tanh_fast(v);
                    const int base = mt * 512 + (kq * 4 + r) * 8 + cbase;
                    state[ks * 2048 + base] = f2bf(v);
                    state[(8 + ks) * 2048 + base] = f2bf(w);
                }
            }
        }
    }

    // ---------------- 8 implicit layers ----------------
    for (int L = 0; L < 8; ++L) {
        const u16* WhL = Wch + (size_t)L * 262144;
        const u16* WlL = Wcl + (size_t)L * 262144;
        float ccv[8];
#pragma unroll
        for (int nt = 0; nt < 8; ++nt)
            ccv[nt] = cc[L * 512 + wave * 128 + nt * 16 + fl];
        f32x4 acc[4][8];
#pragma unroll
        for (int a = 0; a < 4; ++a)
#pragma unroll
            for (int b = 0; b < 8; ++b) acc[a][b] = (f32x4){0.f, 0.f, 0.f, 0.f};
        __syncthreads();   // state ready
#pragma unroll 2
        for (int ks = 0; ks < 16; ++ks) {
            short8 af[4];
#pragma unroll
            for (int mt = 0; mt < 4; ++mt)
                af[mt] = *(const short8*)&state[ks * 2048 + mt * 512 + lane * 8];
#pragma unroll
            for (int nt = 0; nt < 8; ++nt) {
                const size_t wo = (size_t)(wave * 128 + nt * 16 + fl) * 512 + ks * 32 + kq * 8;
                short8 bh = *(const short8*)(WhL + wo);
                short8 bl = *(const short8*)(WlL + wo);
#pragma unroll
                for (int mt = 0; mt < 4; ++mt)
                    acc[mt][nt] = __builtin_amdgcn_mfma_f32_16x16x32_bf16(af[mt], bh, acc[mt][nt], 0, 0, 0);
#pragma unroll
                for (int mt = 0; mt < 4; ++mt)
                    acc[mt][nt] = __builtin_amdgcn_mfma_f32_16x16x32_bf16(af[mt], bl, acc[mt][nt], 0, 0, 0);
            }
        }
        __syncthreads();   // all state reads done; safe to overwrite
        const int p = fl & 1;
        const int uq = fl >> 1;
#pragma unroll
        for (int nt = 0; nt < 8; ++nt) {
            const int u = wave * 64 + nt * 8 + uq;
            const int ks = p ? (8 + (u >> 5)) : (u >> 5);
            const int cbase = ks * 2048 + (((u >> 3) & 3) * 16) * 8 + (u & 7);
#pragma unroll
            for (int mt = 0; mt < 4; ++mt) {
#pragma unroll
                for (int r = 0; r < 4; ++r) {
                    float val = acc[mt][nt][r] + ccv[nt];
                    float tv = tanh_fast(val);
                    float tp = __shfl_xor(tv, 1);
                    float outv = p ? (val + tp) : val;
                    state[cbase + mt * 512 + (kq * 4 + r) * 8] = f2bf(outv);
                }
            }
        }
    }

    // ---------------- output stage: out = v0 @ W_out + b_out ----------------
    __syncthreads();
    for (int i = t; i < 2560; i += 256) aux[i] = Wo[i];
    __syncthreads();
#pragma unroll
    for (int half = 0; half < 2; ++half) {
        const int m = (t >> 3) + half * 32;
        const int o = t & 7;
        float s = bo[o];
        for (int kb = 0; kb < 256; kb += 8) {
            const int off = (kb >> 5) * 2048 + (m >> 4) * 512 +
                            (((kb >> 3) & 3) * 16 + (m & 15)) * 8;
            ushort4 h0 = *(const ushort4*)&state[off];
            ushort4 h1 = *(const ushort4*)&state[off + 4];
            s += bf2f(h0.x) * aux[(kb + 0) * 10 + o] + bf2f(h0.y) * aux[(kb + 1) * 10 + o]
               + bf2f(h0.z) * aux[(kb + 2) * 10 + o] + bf2f(h0.w) * aux[(kb + 3) * 10 + o]
               + bf2f(h1.x) * aux[(kb + 4) * 10 + o] + bf2f(h1.y) * aux[(kb + 5) * 10 + o]
               + bf2f(h1.z) * aux[(kb + 6) * 10 + o] + bf2f(h1.w) * aux[(kb + 7) * 10 + o];
        }
        out[(size_t)(b0 + m) * 10 + o] = s;
    }
    if (t < 128) {
        const int m = t >> 1;
        const int o = 8 + (t & 1);
        float s = bo[o];
        for (int kb = 0; kb < 256; kb += 8) {
            const int off = (kb >> 5) * 2048 + (m >> 4) * 512 +
                            (((kb >> 3) & 3) * 16 + (m & 15)) * 8;
            ushort4 h0 = *(const ushort4*)&state[off];
            ushort4 h1 = *(const ushort4*)&state[off + 4];
            s += bf2f(h0.x) * aux[(kb + 0) * 10 + o] + bf2f(h0.y) * aux[(kb + 1) * 10 + o]
               + bf2f(h0.z) * aux[(kb + 2) * 10 + o] + bf2f(h0.w) * aux[(kb + 3) * 10 + o]
               + bf2f(h1.x) * aux[(kb + 4) * 10 + o] + bf2f(h1.y) * aux[(kb + 5) * 10 + o]
               + bf2f(h1.z) * aux[(kb + 6) * 10 + o] + bf2f(h1.w) * aux[(kb + 7) * 10 + o];
        }
        out[(size_t)(b0 + m) * 10 + o] = s;
    }
}

// ============================================================================
// fp32 prep (small 256x256 batched): D[u,v] = EPI(sum_k A[k][u]*B[k][v])
// ============================================================================
template<int EPI>
__launch_bounds__(256)
__global__ void gemm256b(float* __restrict__ D, const float* __restrict__ A,
                         const float* __restrict__ Bm, const float* __restrict__ E)
{
    __shared__ float As[16][64];
    __shared__ float Bs[16][64];
    const int i = blockIdx.z;
    const size_t off = (size_t)i * 65536;
    const float* Ai = A + off;
    const float* Bi = Bm + off;
    const int t  = threadIdx.x;
    const int tx = t & 15, ty = t >> 4;
    const int u0 = blockIdx.y * 64, v0 = blockIdx.x * 64;
    const int lk = t >> 4, lv = (t & 15) << 2;

    float acc[4][4];
#pragma unroll
    for (int m = 0; m < 4; ++m)
#pragma unroll
        for (int n = 0; n < 4; ++n) acc[m][n] = 0.f;

    for (int k0 = 0; k0 < 256; k0 += 16) {
        __syncthreads();
        *(float4*)&As[lk][lv] = *(const float4*)(Ai + (size_t)(k0 + lk) * 256 + u0 + lv);
        *(float4*)&Bs[lk][lv] = *(const float4*)(Bi + (size_t)(k0 + lk) * 256 + v0 + lv);
        __syncthreads();
#pragma unroll
        for (int kk = 0; kk < 16; ++kk) {
            float af[4], bf[4];
            *(float4*)&af[0] = *(const float4*)&As[kk][ty * 4];
            *(float4*)&bf[0] = *(const float4*)&Bs[kk][tx * 4];
#pragma unroll
            for (int m = 0; m < 4; ++m)
#pragma unroll
                for (int n = 0; n < 4; ++n) acc[m][n] += af[m] * bf[n];
        }
    }

#pragma unroll
    for (int m = 0; m < 4; ++m) {
        const int u = u0 + ty * 4 + m;
        const size_t idx = off + (size_t)u * 256 + v0 + tx * 4;
        float4 r; float* rf = &r.x;
        if (EPI == 0) {
#pragma unroll
            for (int n = 0; n < 4; ++n) rf[n] = acc[m][n];
        } else if (EPI == 1) {
#pragma unroll
            for (int n = 0; n < 4; ++n)
                rf[n] = acc[m][n] + ((u == v0 + tx * 4 + n) ? 2.f : 0.f);
        } else {
            float4 e = *(const float4*)&E[idx];
            const float* ef = &e.x;
#pragma unroll
            for (int n = 0; n < 4; ++n) rf[n] = 2.f * ef[n] - acc[m][n];
        }
        *(float4*)&D[idx] = r;
    }
}

__launch_bounds__(256)
__global__ void transpose256(const float* __restrict__ src, float* __restrict__ dst)
{
    __shared__ float tl[32][33];
    const int i = blockIdx.z;
    const float* S = src + (size_t)i * 65536;
    float* Dst = dst + (size_t)i * 65536;
    const int u0 = blockIdx.y * 32, k0 = blockIdx.x * 32;
    const int tx = threadIdx.x, ty = threadIdx.y; // 32 x 8
#pragma unroll
    for (int r = 0; r < 32; r += 8) tl[ty + r][tx] = S[(size_t)(u0 + ty + r) * 256 + k0 + tx];
    __syncthreads();
#pragma unroll
    for (int r = 0; r < 32; r += 8) Dst[(size_t)(k0 + ty + r) * 256 + u0 + tx] = tl[tx][ty + r];
}

__launch_bounds__(256)
__global__ void bq_kernel(const float* __restrict__ B0, const float* __restrict__ q,
                          float* __restrict__ bq)
{
    __shared__ float qs[256];
    const int i = blockIdx.x;
    const int u = threadIdx.x;
    qs[u] = q[i * 256 + u];
    __syncthreads();
    float s = 0.f;
    for (int k = 0; k < 256; ++k) s += B0[(size_t)i * 65536 + (size_t)k * 256 + u] * qs[k];
    bq[i * 256 + u] = 0.1f * s;
}

// c1 = M bq (M symmetric); odd cc slots
__launch_bounds__(256)
__global__ void cc1_kernel(const float* __restrict__ M, const float* __restrict__ bq,
                           float* __restrict__ c1, float* __restrict__ cc)
{
    __shared__ float vs[256];
    const int i = blockIdx.x;
    const int u = threadIdx.x;
    vs[u] = bq[i * 256 + u];
    __syncthreads();
    float s = 0.f;
    for (int k = 0; k < 256; ++k) s += M[(size_t)i * 65536 + (size_t)k * 256 + u] * vs[k];
    c1[i * 256 + u] = s;
    cc[i * 512 + 2 * u + 1] = s;
}

// c0 = 0.1 q - B c1 ; even cc slots (Bt for coalesced access)
__launch_bounds__(256)
__global__ void cc0_kernel(const float* __restrict__ Bt, const float* __restrict__ q,
                           const float* __restrict__ c1, float* __restrict__ cc)
{
    __shared__ float vs[256];
    const int i = blockIdx.x;
    const int u = threadIdx.x;
    vs[u] = c1[i * 256 + u];
    __syncthreads();
    float s = 0.f;
    for (int k = 0; k < 256; ++k) s += Bt[(size_t)i * 65536 + (size_t)k * 256 + u] * vs[k];
    cc[i * 512 + 2 * u] = 0.1f * q[i * 256 + u] - s;
}

__launch_bounds__(256)
__global__ void alpha_kernel(const float* __restrict__ C, float* __restrict__ alpha)
{
    __shared__ float red[256];
    const int i = blockIdx.x;
    const int u = threadIdx.x;
    float s = 0.f;
    for (int v = 0; v < 256; ++v) s += fabsf(C[(size_t)i * 65536 + (size_t)v * 256 + u]);
    red[u] = s;
    __syncthreads();
    for (int off = 128; off > 0; off >>= 1) {
        if (u < off) red[u] = fmaxf(red[u], red[u + off]);
        __syncthreads();
    }
    if (u == 0) alpha[i] = red[0];
}

__launch_bounds__(256)
__global__ void init_X(float* __restrict__ X, const float* __restrict__ alpha)
{
    const int i = blockIdx.y;
    const float beta = 2.f / (2.f + alpha[i]);
    const int idx4 = (blockIdx.x * 256 + threadIdx.x) * 4;
    const int u = idx4 >> 8;
    const int v = idx4 & 255;
    float4 r;
    r.x = (v     == u) ? beta : 0.f;
    r.y = (v + 1 == u) ? beta : 0.f;
    r.z = (v + 2 == u) ? beta : 0.f;
    r.w = (v + 3 == u) ? beta : 0.f;
    *(float4*)&X[(size_t)i * 65536 + idx4] = r;
}

// Wcomb pack Wpk[i][c][k] hi/lo (interleaved z0/z1 columns)
__launch_bounds__(256)
__global__ void pack_wcomb(const float* __restrict__ P, const float* __restrict__ R,
                           const float* __restrict__ M,
                           u16* __restrict__ Wh, u16* __restrict__ Wl)
{
    const int i = blockIdx.y;
    const int e = blockIdx.x * 256 + threadIdx.x;   // 0..262143
    const int c = e >> 9, k = e & 511;
    const int u = c >> 1, parity = c & 1;
    const size_t off = (size_t)i * 65536;
    float v;
    if (parity == 0) {
        if (k < 256) v = ((u == k) ? 1.f : 0.f) - R[off + (size_t)u * 256 + k];
        else         v = -P[off + (size_t)(k - 256) * 256 + u];
    } else {
        if (k < 256) v = P[off + (size_t)u * 256 + k];
        else         v = M[off + (size_t)u * 256 + (k - 256)];
    }
    u16 h, l; fsplit(v, h, l);
    const size_t o = (size_t)i * 262144 + (size_t)c * 512 + k;
    Wh[o] = h; Wl[o] = l;
}

// W_in [784][256] -> Wpack [256 u][800 k] (transposed, zero-padded), bf16 hi/lo
__global__ void pack_win(const float* __restrict__ Wi, u16* __restrict__ h, u16* __restrict__ l)
{
    int k = blockIdx.x * 256 + threadIdx.x;
    int u = blockIdx.y;
    if (k >= 800) return;
    float v = (k < 784) ? Wi[(size_t)k * 256 + u] : 0.f;
    u16 hh, ll; fsplit(v, hh, ll);
    h[(size_t)u * 800 + k] = hh;
    l[(size_t)u * 800 + k] = ll;
}

extern "C" void kernel_launch(void* const* d_in, const int* in_sizes, int n_in,
                              void* d_out, int out_size, void* d_ws, size_t ws_size,
                              hipStream_t stream)
{
    const float* x     = (const float*)d_in[0];
    const float* W_in  = (const float*)d_in[1];
    const float* b_in  = (const float*)d_in[2];
    const float* B0    = (const float*)d_in[3];
    const float* q     = (const float*)d_in[4];
    const float* W_out = (const float*)d_in[5];
    const float* b_out = (const float*)d_in[6];

    u16* Wch = (u16*)d_ws;               // 8 * 262144
    u16* Wcl = Wch + 8 * 262144;
    u16* Wih = Wcl + 8 * 262144;         // 256*800
    u16* Wil = Wih + 204800;
    float* bq    = (float*)(Wil + 204800);
    float* alpha = bq + 2048;
    float* c1    = alpha + 16;
    float* cc    = c1 + 2048;            // 8*512
    float* F     = cc + 4096;            // prep scratch: 7 * 524288 floats
    float* Bt = F;
    float* C  = F + 1 * 524288;
    float* X  = F + 2 * 524288;
    float* X2 = F + 3 * 524288;
    float* Y  = F + 4 * 524288;
    float* P  = F + 5 * 524288;
    float* R  = F + 6 * 524288;

    // ---- per-layer matrix prep (fp32) ----
    transpose256<<<dim3(8, 8, 8), dim3(32, 8), 0, stream>>>(B0, Bt);
    bq_kernel<<<8, 256, 0, stream>>>(B0, q, bq);
    gemm256b<1><<<dim3(4, 4, 8), 256, 0, stream>>>(C, B0, B0, nullptr); // C = B^T B + 2I
    alpha_kernel<<<8, 256, 0, stream>>>(C, alpha);
    init_X<<<dim3(64, 8), 256, 0, stream>>>(X, alpha);
    float* Xc = X; float* Xn = X2;
    for (int it = 0; it < 6; ++it) {   // Newton-Schulz: X <- 2X - X C X
        gemm256b<0><<<dim3(4, 4, 8), 256, 0, stream>>>(Y, C, Xc, nullptr);
        gemm256b<2><<<dim3(4, 4, 8), 256, 0, stream>>>(Xn, Xc, Y, Xc);
        float* tmp = Xc; Xc = Xn; Xn = tmp;
    }
    // Xc = M = (B^T B + 2I)^{-1} (symmetric)
    gemm256b<0><<<dim3(4, 4, 8), 256, 0, stream>>>(P, Xc, Bt, nullptr);  // P = M B^T
    gemm256b<0><<<dim3(4, 4, 8), 256, 0, stream>>>(R, Bt, P, nullptr);   // R = B P
    cc1_kernel<<<8, 256, 0, stream>>>(Xc, bq, c1, cc);                   // c1 = M bq
    cc0_kernel<<<8, 256, 0, stream>>>(Bt, q, c1, cc);                    // c0 = 0.1q - B c1

    // ---- weight packs ----
    pack_wcomb<<<dim3(1024, 8), 256, 0, stream>>>(P, R, Xc, Wch, Wcl);
    pack_win<<<dim3(4, 256), 256, 0, stream>>>(W_in, Wih, Wil);

    // ---- the whole network in one kernel ----
    meganet<<<BATCH_N / 64, 256, 0, stream>>>(
        x, Wih, Wil, b_in, Wch, Wcl, cc, W_out, b_out, (float*)d_out);
}

// Round 5
// 1024.355 us; speedup vs baseline: 1.7144x; 1.1031x over previous
//
#include <hip/hip_runtime.h>
#include <cstddef>
#include <cstdint>

#define BATCH_N 32768
#define OUT_DIM 10

typedef unsigned short u16;
typedef __attribute__((ext_vector_type(8))) short short8;
typedef __attribute__((ext_vector_type(4))) float f32x4;

__device__ __forceinline__ float bf2f(u16 h) {
    return __uint_as_float(((uint32_t)h) << 16);
}
__device__ __forceinline__ u16 f2bf(float v) {
    uint32_t b = __float_as_uint(v);
    b += 0x7FFFu + ((b >> 16) & 1u);
    return (u16)(b >> 16);
}
__device__ __forceinline__ void fsplit(float v, u16& h, u16& l) {
    h = f2bf(v);
    l = f2bf(v - bf2f(h));
}
__device__ __forceinline__ float tanh_fast(float x) {
    float e = __expf(2.f * x);        // inf -> 1, 0 -> -1 : robust
    return 1.f - 2.f / (e + 1.f);
}

// ============================================================================
// MEGA-FUSED NETWORK KERNEL (R5: imm-offset weight loads).
// Block owns 64 batch rows; [v0 ; w] state (64 x 512 bf16) lives in LDS in
// MFMA A-fragment layout: element (m,k) -> state[(k>>5)*2048 + (m>>4)*512 +
// (((k>>3)&3)*16 + (m&15))*8 + (k&7)].
// Weights: Wc[layer][col c][1024]: k 0..511 = hi bf16, 512..1023 = lo bf16.
// Per (wave,nt) ONE base pointer per layer; every load in the fully-unrolled
// ks loop uses a compile-time immediate offset (hi: ks*64 B, lo: 1024+ks*64 B).
// Columns interleaved: c=2u -> z0[u], c=2u+1 -> z1[u]; epilogue adds cc[c],
// hands tanh(z0) even->odd lane via shfl_xor(1), writes v0'=z0, w'=z1+tanh(z0).
// ============================================================================
__global__ __launch_bounds__(256, 2)
void meganet(const float* __restrict__ X,
             const u16* __restrict__ Wi,        // [256 u][1600] hi|lo
             const float* __restrict__ b_in,
             const u16* __restrict__ Wc,        // [8][512 c][1024] hi|lo
             const float* __restrict__ cc,
             const float* __restrict__ Wo, const float* __restrict__ bo,
             float* __restrict__ out)
{
    __shared__ u16 state[32768];     // 64 KB
    __shared__ float aux[2560];      // 10 KB: x staging, later W_out copy
    const int t = threadIdx.x;
    const int wave = t >> 6, lane = t & 63;
    const int fl = lane & 15, kq = lane >> 4;
    const int b0 = blockIdx.x * 64;

    // ---------------- input stage: v0 = x @ W_in + b_in (K=784, pad 800) ----
    f32x4 ai[4][4];
#pragma unroll
    for (int a = 0; a < 4; ++a)
#pragma unroll
        for (int b = 0; b < 4; ++b) ai[a][b] = (f32x4){0.f, 0.f, 0.f, 0.f};

    const u16* bpIn[4];
#pragma unroll
    for (int nt = 0; nt < 4; ++nt)
        bpIn[nt] = Wi + (size_t)(wave * 64 + nt * 16 + fl) * 1600 + kq * 8;

    u16* xbuf = (u16*)aux;           // 2048 u16 chunk buffer
    const int xr = t >> 2;           // row 0..63
    const int xk = (t & 3) * 8;      // 0,8,16,24
    const size_t xrow = (size_t)(b0 + xr) * 784;

#pragma unroll
    for (int k0 = 0; k0 < 800; k0 += 32) {
        const int gk = k0 + xk;
        const int ga = (gk <= 776) ? gk : 776;   // clamp; W_in pack 0 for k>=784
        __syncthreads();
        float4 xa = *(const float4*)(X + xrow + ga);
        float4 xb = *(const float4*)(X + xrow + ga + 4);
        const int off = (xr >> 4) * 512 + ((xk >> 3) * 16 + (xr & 15)) * 8;
        ushort4 ha, hb;
        ha.x = f2bf(xa.x); ha.y = f2bf(xa.y); ha.z = f2bf(xa.z); ha.w = f2bf(xa.w);
        hb.x = f2bf(xb.x); hb.y = f2bf(xb.y); hb.z = f2bf(xb.z); hb.w = f2bf(xb.w);
        *(ushort4*)&xbuf[off] = ha;
        *(ushort4*)&xbuf[off + 4] = hb;
        __syncthreads();
        short8 af[4];
#pragma unroll
        for (int mt = 0; mt < 4; ++mt)
            af[mt] = *(const short8*)&xbuf[mt * 512 + lane * 8];
#pragma unroll
        for (int nt = 0; nt < 4; ++nt) {
            short8 bh = *(const short8*)(bpIn[nt] + k0);
            short8 bl = *(const short8*)(bpIn[nt] + 800 + k0);
#pragma unroll
            for (int mt = 0; mt < 4; ++mt) {
                ai[mt][nt] = __builtin_amdgcn_mfma_f32_16x16x32_bf16(af[mt], bh, ai[mt][nt], 0, 0, 0);
                ai[mt][nt] = __builtin_amdgcn_mfma_f32_16x16x32_bf16(af[mt], bl, ai[mt][nt], 0, 0, 0);
            }
        }
    }
    // input epilogue: state v0 (k=u), w = 2*tanh(v0) (k=256+u)
    {
        float bi[4];
#pragma unroll
        for (int nt = 0; nt < 4; ++nt) bi[nt] = b_in[wave * 64 + nt * 16 + fl];
#pragma unroll
        for (int nt = 0; nt < 4; ++nt) {
            const int u = wave * 64 + nt * 16 + fl;
            const int ks = u >> 5;
            const int cbase = (((u >> 3) & 3) * 16) * 8 + (u & 7);
#pragma unroll
            for (int mt = 0; mt < 4; ++mt) {
#pragma unroll
                for (int r = 0; r < 4; ++r) {
                    float v = ai[mt][nt][r] + bi[nt];
                    float w = 2.f * tanh_fast(v);
                    const int base = mt * 512 + (kq * 4 + r) * 8 + cbase;
                    state[ks * 2048 + base] = f2bf(v);
                    state[(8 + ks) * 2048 + base] = f2bf(w);
                }
            }
        }
    }

    // ---------------- 8 implicit layers ----------------
    for (int L = 0; L < 8; ++L) {
        const u16* WL = Wc + (size_t)L * 524288;
        const u16* bp[8];
#pragma unroll
        for (int nt = 0; nt < 8; ++nt)
            bp[nt] = WL + (size_t)(wave * 128 + nt * 16 + fl) * 1024 + kq * 8;
        float ccv[8];
#pragma unroll
        for (int nt = 0; nt < 8; ++nt)
            ccv[nt] = cc[L * 512 + wave * 128 + nt * 16 + fl];
        f32x4 acc[4][8];
#pragma unroll
        for (int a = 0; a < 4; ++a)
#pragma unroll
            for (int b = 0; b < 8; ++b) acc[a][b] = (f32x4){0.f, 0.f, 0.f, 0.f};
        __syncthreads();   // state ready
#pragma unroll
        for (int ks = 0; ks < 16; ++ks) {
            short8 af[4];
#pragma unroll
            for (int mt = 0; mt < 4; ++mt)
                af[mt] = *(const short8*)&state[ks * 2048 + mt * 512 + lane * 8];
#pragma unroll
            for (int nt = 0; nt < 8; ++nt) {
                short8 bh = *(const short8*)(bp[nt] + ks * 32);         // imm: ks*64 B
                short8 bl = *(const short8*)(bp[nt] + 512 + ks * 32);   // imm: 1024+ks*64 B
#pragma unroll
                for (int mt = 0; mt < 4; ++mt)
                    acc[mt][nt] = __builtin_amdgcn_mfma_f32_16x16x32_bf16(af[mt], bh, acc[mt][nt], 0, 0, 0);
#pragma unroll
                for (int mt = 0; mt < 4; ++mt)
                    acc[mt][nt] = __builtin_amdgcn_mfma_f32_16x16x32_bf16(af[mt], bl, acc[mt][nt], 0, 0, 0);
            }
        }
        __syncthreads();   // all state reads done; safe to overwrite
        const int p = fl & 1;
        const int uq = fl >> 1;
#pragma unroll
        for (int nt = 0; nt < 8; ++nt) {
            const int u = wave * 64 + nt * 8 + uq;
            const int ks = p ? (8 + (u >> 5)) : (u >> 5);
            const int cbase = ks * 2048 + (((u >> 3) & 3) * 16) * 8 + (u & 7);
#pragma unroll
            for (int mt = 0; mt < 4; ++mt) {
#pragma unroll
                for (int r = 0; r < 4; ++r) {
                    float val = acc[mt][nt][r] + ccv[nt];
                    float tv = tanh_fast(val);
                    float tp = __shfl_xor(tv, 1);
                    float outv = p ? (val + tp) : val;
                    state[cbase + mt * 512 + (kq * 4 + r) * 8] = f2bf(outv);
                }
            }
        }
    }

    // ---------------- output stage: out = v0 @ W_out + b_out ----------------
    __syncthreads();
    for (int i = t; i < 2560; i += 256) aux[i] = Wo[i];
    __syncthreads();
#pragma unroll
    for (int half = 0; half < 2; ++half) {
        const int m = (t >> 3) + half * 32;
        const int o = t & 7;
        float s = bo[o];
        for (int kb = 0; kb < 256; kb += 8) {
            const int off = (kb >> 5) * 2048 + (m >> 4) * 512 +
                            (((kb >> 3) & 3) * 16 + (m & 15)) * 8;
            ushort4 h0 = *(const ushort4*)&state[off];
            ushort4 h1 = *(const ushort4*)&state[off + 4];
            s += bf2f(h0.x) * aux[(kb + 0) * 10 + o] + bf2f(h0.y) * aux[(kb + 1) * 10 + o]
               + bf2f(h0.z) * aux[(kb + 2) * 10 + o] + bf2f(h0.w) * aux[(kb + 3) * 10 + o]
               + bf2f(h1.x) * aux[(kb + 4) * 10 + o] + bf2f(h1.y) * aux[(kb + 5) * 10 + o]
               + bf2f(h1.z) * aux[(kb + 6) * 10 + o] + bf2f(h1.w) * aux[(kb + 7) * 10 + o];
        }
        out[(size_t)(b0 + m) * 10 + o] = s;
    }
    if (t < 128) {
        const int m = t >> 1;
        const int o = 8 + (t & 1);
        float s = bo[o];
        for (int kb = 0; kb < 256; kb += 8) {
            const int off = (kb >> 5) * 2048 + (m >> 4) * 512 +
                            (((kb >> 3) & 3) * 16 + (m & 15)) * 8;
            ushort4 h0 = *(const ushort4*)&state[off];
            ushort4 h1 = *(const ushort4*)&state[off + 4];
            s += bf2f(h0.x) * aux[(kb + 0) * 10 + o] + bf2f(h0.y) * aux[(kb + 1) * 10 + o]
               + bf2f(h0.z) * aux[(kb + 2) * 10 + o] + bf2f(h0.w) * aux[(kb + 3) * 10 + o]
               + bf2f(h1.x) * aux[(kb + 4) * 10 + o] + bf2f(h1.y) * aux[(kb + 5) * 10 + o]
               + bf2f(h1.z) * aux[(kb + 6) * 10 + o] + bf2f(h1.w) * aux[(kb + 7) * 10 + o];
        }
        out[(size_t)(b0 + m) * 10 + o] = s;
    }
}

// ============================================================================
// fp32 prep: D[u,v] = EPI(sum_k A[k][u]*B[k][v]) batched over 8
// ============================================================================
template<int EPI>
__launch_bounds__(256)
__global__ void gemm256b(float* __restrict__ D, const float* __restrict__ A,
                         const float* __restrict__ Bm, const float* __restrict__ E)
{
    __shared__ float As[16][64];
    __shared__ float Bs[16][64];
    const int i = blockIdx.z;
    const size_t off = (size_t)i * 65536;
    const float* Ai = A + off;
    const float* Bi = Bm + off;
    const int t  = threadIdx.x;
    const int tx = t & 15, ty = t >> 4;
    const int u0 = blockIdx.y * 64, v0 = blockIdx.x * 64;
    const int lk = t >> 4, lv = (t & 15) << 2;

    float acc[4][4];
#pragma unroll
    for (int m = 0; m < 4; ++m)
#pragma unroll
        for (int n = 0; n < 4; ++n) acc[m][n] = 0.f;

    for (int k0 = 0; k0 < 256; k0 += 16) {
        __syncthreads();
        *(float4*)&As[lk][lv] = *(const float4*)(Ai + (size_t)(k0 + lk) * 256 + u0 + lv);
        *(float4*)&Bs[lk][lv] = *(const float4*)(Bi + (size_t)(k0 + lk) * 256 + v0 + lv);
        __syncthreads();
#pragma unroll
        for (int kk = 0; kk < 16; ++kk) {
            float af[4], bf[4];
            *(float4*)&af[0] = *(const float4*)&As[kk][ty * 4];
            *(float4*)&bf[0] = *(const float4*)&Bs[kk][tx * 4];
#pragma unroll
            for (int m = 0; m < 4; ++m)
#pragma unroll
                for (int n = 0; n < 4; ++n) acc[m][n] += af[m] * bf[n];
        }
    }

#pragma unroll
    for (int m = 0; m < 4; ++m) {
        const int u = u0 + ty * 4 + m;
        const size_t idx = off + (size_t)u * 256 + v0 + tx * 4;
        float4 r; float* rf = &r.x;
        if (EPI == 0) {
#pragma unroll
            for (int n = 0; n < 4; ++n) rf[n] = acc[m][n];
        } else if (EPI == 1) {
#pragma unroll
            for (int n = 0; n < 4; ++n)
                rf[n] = acc[m][n] + ((u == v0 + tx * 4 + n) ? 2.f : 0.f);
        } else {
            float4 e = *(const float4*)&E[idx];
            const float* ef = &e.x;
#pragma unroll
            for (int n = 0; n < 4; ++n) rf[n] = 2.f * ef[n] - acc[m][n];
        }
        *(float4*)&D[idx] = r;
    }
}

// transpose (Bt[k][u] = B0[u][k]) + bq = 0.1 * B0^T-col-weighted q : 1 launch
__launch_bounds__(256)
__global__ void prep_bt_bq(const float* __restrict__ B0, const float* __restrict__ q,
                           float* __restrict__ Bt, float* __restrict__ bq)
{
    __shared__ float tl[32][33];
    __shared__ float qs[256];
    const int i = blockIdx.x;
    const float* S = B0 + (size_t)i * 65536;
    float* D = Bt + (size_t)i * 65536;
    const int t = threadIdx.x;
    const int tx = t & 31, ty = t >> 5;   // 32 x 8
    for (int tile = 0; tile < 64; ++tile) {
        const int u0 = (tile >> 3) * 32, k0 = (tile & 7) * 32;
        __syncthreads();
#pragma unroll
        for (int r = 0; r < 32; r += 8)
            tl[ty + r][tx] = S[(size_t)(u0 + ty + r) * 256 + k0 + tx];
        __syncthreads();
#pragma unroll
        for (int r = 0; r < 32; r += 8)
            D[(size_t)(k0 + ty + r) * 256 + u0 + tx] = tl[tx][ty + r];
    }
    __syncthreads();
    qs[t] = q[i * 256 + t];
    __syncthreads();
    float s = 0.f;
    for (int k = 0; k < 256; ++k) s += S[(size_t)k * 256 + t] * qs[k];
    bq[i * 256 + t] = 0.1f * s;
}

// alpha = ||C||_inf then X0 = (2/(2+alpha)) I : 1 launch
__launch_bounds__(256)
__global__ void prep_alpha_init(const float* __restrict__ C, float* __restrict__ X)
{
    __shared__ float red[256];
    const int i = blockIdx.x;
    const int t = threadIdx.x;
    float s = 0.f;
    for (int v = 0; v < 256; ++v) s += fabsf(C[(size_t)i * 65536 + (size_t)v * 256 + t]);
    red[t] = s;
    __syncthreads();
    for (int off = 128; off > 0; off >>= 1) {
        if (t < off) red[t] = fmaxf(red[t], red[t + off]);
        __syncthreads();
    }
    const float beta = 2.f / (2.f + red[0]);
    for (int e = t; e < 65536; e += 256) {
        const int r_ = e >> 8, c_ = e & 255;
        X[(size_t)i * 65536 + e] = (r_ == c_) ? beta : 0.f;
    }
}

// c1 = M bq (odd cc slots), then c0 = 0.1 q - B c1 (even slots) : 1 launch
__launch_bounds__(256)
__global__ void prep_cc(const float* __restrict__ M, const float* __restrict__ Bt,
                        const float* __restrict__ bq, const float* __restrict__ q,
                        float* __restrict__ cc)
{
    __shared__ float vs[256];
    __shared__ float c1s[256];
    const int i = blockIdx.x;
    const int u = threadIdx.x;
    vs[u] = bq[i * 256 + u];
    __syncthreads();
    float s = 0.f;
    for (int k = 0; k < 256; ++k) s += M[(size_t)i * 65536 + (size_t)k * 256 + u] * vs[k];
    c1s[u] = s;
    cc[i * 512 + 2 * u + 1] = s;
    __syncthreads();
    float s2 = 0.f;
    for (int k = 0; k < 256; ++k) s2 += Bt[(size_t)i * 65536 + (size_t)k * 256 + u] * c1s[k];
    cc[i * 512 + 2 * u] = 0.1f * q[i * 256 + u] - s2;
}

// Wc[i][c][1024] hi|lo pack (interleaved z0/z1 columns)
__launch_bounds__(256)
__global__ void pack_wcomb(const float* __restrict__ P, const float* __restrict__ R,
                           const float* __restrict__ M, u16* __restrict__ W)
{
    const int i = blockIdx.y;
    const int e = blockIdx.x * 256 + threadIdx.x;   // 0..262143
    const int c = e >> 9, k = e & 511;
    const int u = c >> 1, parity = c & 1;
    const size_t off = (size_t)i * 65536;
    float v;
    if (parity == 0) {
        if (k < 256) v = ((u == k) ? 1.f : 0.f) - R[off + (size_t)u * 256 + k];
        else         v = -P[off + (size_t)(k - 256) * 256 + u];
    } else {
        if (k < 256) v = P[off + (size_t)u * 256 + k];
        else         v = M[off + (size_t)u * 256 + (k - 256)];
    }
    u16 h, l; fsplit(v, h, l);
    const size_t o = (size_t)i * 524288 + (size_t)c * 1024 + k;
    W[o] = h; W[o + 512] = l;
}

// W_in [784][256] -> Wi[256 u][1600] hi|lo (transposed, zero-padded)
__global__ void pack_win(const float* __restrict__ Wsrc, u16* __restrict__ W)
{
    int k = blockIdx.x * 256 + threadIdx.x;
    int u = blockIdx.y;
    if (k >= 800) return;
    float v = (k < 784) ? Wsrc[(size_t)k * 256 + u] : 0.f;
    u16 h, l; fsplit(v, h, l);
    W[(size_t)u * 1600 + k] = h;
    W[(size_t)u * 1600 + 800 + k] = l;
}

extern "C" void kernel_launch(void* const* d_in, const int* in_sizes, int n_in,
                              void* d_out, int out_size, void* d_ws, size_t ws_size,
                              hipStream_t stream)
{
    const float* x     = (const float*)d_in[0];
    const float* W_in  = (const float*)d_in[1];
    const float* b_in  = (const float*)d_in[2];
    const float* B0    = (const float*)d_in[3];
    const float* q     = (const float*)d_in[4];
    const float* W_out = (const float*)d_in[5];
    const float* b_out = (const float*)d_in[6];

    u16* Wc = (u16*)d_ws;                  // 8 * 524288 u16 = 8 MB
    u16* Wi = Wc + 8 * 524288;             // 256*1600
    float* bq = (float*)(Wi + 409600);
    float* cc = bq + 2048;                 // 8*512
    float* F  = cc + 4096;                 // prep scratch: 7 * 524288 floats
    float* Bt = F;
    float* C  = F + 1 * 524288;
    float* X  = F + 2 * 524288;
    float* X2 = F + 3 * 524288;
    float* Y  = F + 4 * 524288;
    float* P  = F + 5 * 524288;
    float* R  = F + 6 * 524288;

    // ---- per-layer matrix prep (fp32) ----
    prep_bt_bq<<<8, 256, 0, stream>>>(B0, q, Bt, bq);
    gemm256b<1><<<dim3(4, 4, 8), 256, 0, stream>>>(C, B0, B0, nullptr); // C = B^T B + 2I
    prep_alpha_init<<<8, 256, 0, stream>>>(C, X);
    float* Xc = X; float* Xn = X2;
    for (int it = 0; it < 5; ++it) {   // Newton-Schulz: X <- 2X - X C X
        gemm256b<0><<<dim3(4, 4, 8), 256, 0, stream>>>(Y, C, Xc, nullptr);
        gemm256b<2><<<dim3(4, 4, 8), 256, 0, stream>>>(Xn, Xc, Y, Xc);
        float* tmp = Xc; Xc = Xn; Xn = tmp;
    }
    // Xc = M = (B^T B + 2I)^{-1} (symmetric)
    gemm256b<0><<<dim3(4, 4, 8), 256, 0, stream>>>(P, Xc, Bt, nullptr);  // P = M B^T
    gemm256b<0><<<dim3(4, 4, 8), 256, 0, stream>>>(R, Bt, P, nullptr);   // R = B P
    prep_cc<<<8, 256, 0, stream>>>(Xc, Bt, bq, q, cc);

    // ---- weight packs ----
    pack_wcomb<<<dim3(1024, 8), 256, 0, stream>>>(P, R, Xc, Wc);
    pack_win<<<dim3(4, 256), 256, 0, stream>>>(W_in, Wi);

    // ---- the whole network in one kernel ----
    meganet<<<BATCH_N / 64, 256, 0, stream>>>(
        x, Wi, b_in, Wc, cc, W_out, b_out, (float*)d_out);
}

// Round 6
// 919.393 us; speedup vs baseline: 1.9101x; 1.1142x over previous
//
#include <hip/hip_runtime.h>
#include <cstddef>
#include <cstdint>

#define BATCH_N 32768
#define OUT_DIM 10

typedef unsigned short u16;
typedef __attribute__((ext_vector_type(8))) short short8;
typedef __attribute__((ext_vector_type(4))) float f32x4;

__device__ __forceinline__ float bf2f(u16 h) {
    return __uint_as_float(((uint32_t)h) << 16);
}
__device__ __forceinline__ u16 f2bf(float v) {
    uint32_t b = __float_as_uint(v);
    b += 0x7FFFu + ((b >> 16) & 1u);
    return (u16)(b >> 16);
}
__device__ __forceinline__ void fsplit(float v, u16& h, u16& l) {
    h = f2bf(v);
    l = f2bf(v - bf2f(h));
}
__device__ __forceinline__ float tanh_fast(float x) {
    float e = __expf(2.f * x);        // inf -> 1, 0 -> -1 : robust
    return 1.f - 2.f / (e + 1.f);
}

// ============================================================================
// MEGA-FUSED NETWORK KERNEL (R6: 512 threads = 8 waves, 4 waves/SIMD).
// Block owns 64 batch rows; [v0 ; w] state (64 x 512 bf16) in LDS, MFMA
// A-fragment layout: (m,k) -> state[(k>>5)*2048 + (m>>4)*512 +
// (((k>>3)&3)*16 + (m&15))*8 + (k&7)].
// Weights Wc[layer][col c][1024]: k 0..511 hi bf16, 512..1023 lo bf16.
// Layer GEMM: wave owns 64 cols (nt<4), acc[4][4] = 64 VGPRs -> fits
// __launch_bounds__(512,4) cap of 128, giving 2 blocks/CU = 4 waves/SIMD.
// Columns interleaved: c=2u -> z0[u], c=2u+1 -> z1[u]; epilogue adds cc[c],
// hands tanh(z0) even->odd lane via shfl_xor(1), writes v0'=z0, w'=z1+tanh(z0).
// ============================================================================
__global__ __launch_bounds__(512, 4)
void meganet(const float* __restrict__ X,
             const u16* __restrict__ Wi,        // [256 u][1600] hi|lo
             const float* __restrict__ b_in,
             const u16* __restrict__ Wc,        // [8][512 c][1024] hi|lo
             const float* __restrict__ cc,
             const float* __restrict__ Wo, const float* __restrict__ bo,
             float* __restrict__ out)
{
    __shared__ u16 state[32768];     // 64 KB
    __shared__ float aux[2560];      // 10 KB: x staging, later W_out copy
    const int t = threadIdx.x;
    const int wave = t >> 6, lane = t & 63;
    const int fl = lane & 15, kq = lane >> 4;
    const int b0 = blockIdx.x * 64;

    // ---------------- input stage: v0 = x @ W_in + b_in (K=784, pad 800) ----
    // 8 waves x 32 cols (nt<2); acc 4x2
    f32x4 ai[4][2];
#pragma unroll
    for (int a = 0; a < 4; ++a)
#pragma unroll
        for (int b = 0; b < 2; ++b) ai[a][b] = (f32x4){0.f, 0.f, 0.f, 0.f};

    const u16* bpIn[2];
#pragma unroll
    for (int nt = 0; nt < 2; ++nt)
        bpIn[nt] = Wi + (size_t)(wave * 32 + nt * 16 + fl) * 1600 + kq * 8;

    u16* xbuf = (u16*)aux;           // 2048 u16 chunk buffer
    const int xr = t >> 3;           // row 0..63
    const int xk = (t & 7) * 4;      // 0..28 step 4
    const size_t xrow = (size_t)(b0 + xr) * 784;

#pragma unroll
    for (int k0 = 0; k0 < 800; k0 += 32) {
        const int gk = k0 + xk;
        const int ga = (gk <= 780) ? gk : 780;   // clamp; W_in pack 0 for k>=784
        __syncthreads();
        float4 xa = *(const float4*)(X + xrow + ga);
        const int off = (xr >> 4) * 512 + ((xk >> 3) * 16 + (xr & 15)) * 8 + (xk & 7);
        ushort4 ha;
        ha.x = f2bf(xa.x); ha.y = f2bf(xa.y); ha.z = f2bf(xa.z); ha.w = f2bf(xa.w);
        *(ushort4*)&xbuf[off] = ha;
        __syncthreads();
        short8 af[4];
#pragma unroll
        for (int mt = 0; mt < 4; ++mt)
            af[mt] = *(const short8*)&xbuf[mt * 512 + lane * 8];
#pragma unroll
        for (int nt = 0; nt < 2; ++nt) {
            short8 bh = *(const short8*)(bpIn[nt] + k0);
            short8 bl = *(const short8*)(bpIn[nt] + 800 + k0);
#pragma unroll
            for (int mt = 0; mt < 4; ++mt) {
                ai[mt][nt] = __builtin_amdgcn_mfma_f32_16x16x32_bf16(af[mt], bh, ai[mt][nt], 0, 0, 0);
                ai[mt][nt] = __builtin_amdgcn_mfma_f32_16x16x32_bf16(af[mt], bl, ai[mt][nt], 0, 0, 0);
            }
        }
    }
    // input epilogue: state v0 (k=u), w = 2*tanh(v0) (k=256+u)
    {
        float bi[2];
#pragma unroll
        for (int nt = 0; nt < 2; ++nt) bi[nt] = b_in[wave * 32 + nt * 16 + fl];
#pragma unroll
        for (int nt = 0; nt < 2; ++nt) {
            const int u = wave * 32 + nt * 16 + fl;
            const int ks = u >> 5;
            const int cbase = (((u >> 3) & 3) * 16) * 8 + (u & 7);
#pragma unroll
            for (int mt = 0; mt < 4; ++mt) {
#pragma unroll
                for (int r = 0; r < 4; ++r) {
                    float v = ai[mt][nt][r] + bi[nt];
                    float w = 2.f * tanh_fast(v);
                    const int base = mt * 512 + (kq * 4 + r) * 8 + cbase;
                    state[ks * 2048 + base] = f2bf(v);
                    state[(8 + ks) * 2048 + base] = f2bf(w);
                }
            }
        }
    }

    // ---------------- 8 implicit layers ----------------
    for (int L = 0; L < 8; ++L) {
        const u16* WL = Wc + (size_t)L * 524288;
        const u16* bp[4];
#pragma unroll
        for (int nt = 0; nt < 4; ++nt)
            bp[nt] = WL + (size_t)(wave * 64 + nt * 16 + fl) * 1024 + kq * 8;
        float ccv[4];
#pragma unroll
        for (int nt = 0; nt < 4; ++nt)
            ccv[nt] = cc[L * 512 + wave * 64 + nt * 16 + fl];
        f32x4 acc[4][4];
#pragma unroll
        for (int a = 0; a < 4; ++a)
#pragma unroll
            for (int b = 0; b < 4; ++b) acc[a][b] = (f32x4){0.f, 0.f, 0.f, 0.f};
        __syncthreads();   // state ready
#pragma unroll
        for (int ks = 0; ks < 16; ++ks) {
            short8 af[4];
#pragma unroll
            for (int mt = 0; mt < 4; ++mt)
                af[mt] = *(const short8*)&state[ks * 2048 + mt * 512 + lane * 8];
#pragma unroll
            for (int nt = 0; nt < 4; ++nt) {
                short8 bh = *(const short8*)(bp[nt] + ks * 32);         // imm offs
                short8 bl = *(const short8*)(bp[nt] + 512 + ks * 32);   // imm offs
#pragma unroll
                for (int mt = 0; mt < 4; ++mt)
                    acc[mt][nt] = __builtin_amdgcn_mfma_f32_16x16x32_bf16(af[mt], bh, acc[mt][nt], 0, 0, 0);
#pragma unroll
                for (int mt = 0; mt < 4; ++mt)
                    acc[mt][nt] = __builtin_amdgcn_mfma_f32_16x16x32_bf16(af[mt], bl, acc[mt][nt], 0, 0, 0);
            }
        }
        __syncthreads();   // all state reads done; safe to overwrite
        const int p = fl & 1;
        const int uq = fl >> 1;
#pragma unroll
        for (int nt = 0; nt < 4; ++nt) {
            const int u = wave * 32 + nt * 8 + uq;
            const int ks = p ? (8 + (u >> 5)) : (u >> 5);
            const int cbase = ks * 2048 + (((u >> 3) & 3) * 16) * 8 + (u & 7);
#pragma unroll
            for (int mt = 0; mt < 4; ++mt) {
#pragma unroll
                for (int r = 0; r < 4; ++r) {
                    float val = acc[mt][nt][r] + ccv[nt];
                    float tv = tanh_fast(val);
                    float tp = __shfl_xor(tv, 1);
                    float outv = p ? (val + tp) : val;
                    state[cbase + mt * 512 + (kq * 4 + r) * 8] = f2bf(outv);
                }
            }
        }
    }

    // ---------------- output stage: out = v0 @ W_out + b_out ----------------
    __syncthreads();
    for (int i = t; i < 2560; i += 512) aux[i] = Wo[i];
    __syncthreads();
    {
        const int m = t >> 3;        // 0..63
        const int o = t & 7;
        float s = bo[o];
        for (int kb = 0; kb < 256; kb += 8) {
            const int off = (kb >> 5) * 2048 + (m >> 4) * 512 +
                            (((kb >> 3) & 3) * 16 + (m & 15)) * 8;
            ushort4 h0 = *(const ushort4*)&state[off];
            ushort4 h1 = *(const ushort4*)&state[off + 4];
            s += bf2f(h0.x) * aux[(kb + 0) * 10 + o] + bf2f(h0.y) * aux[(kb + 1) * 10 + o]
               + bf2f(h0.z) * aux[(kb + 2) * 10 + o] + bf2f(h0.w) * aux[(kb + 3) * 10 + o]
               + bf2f(h1.x) * aux[(kb + 4) * 10 + o] + bf2f(h1.y) * aux[(kb + 5) * 10 + o]
               + bf2f(h1.z) * aux[(kb + 6) * 10 + o] + bf2f(h1.w) * aux[(kb + 7) * 10 + o];
        }
        out[(size_t)(b0 + m) * 10 + o] = s;
    }
    if (t < 128) {
        const int m = t >> 1;
        const int o = 8 + (t & 1);
        float s = bo[o];
        for (int kb = 0; kb < 256; kb += 8) {
            const int off = (kb >> 5) * 2048 + (m >> 4) * 512 +
                            (((kb >> 3) & 3) * 16 + (m & 15)) * 8;
            ushort4 h0 = *(const ushort4*)&state[off];
            ushort4 h1 = *(const ushort4*)&state[off + 4];
            s += bf2f(h0.x) * aux[(kb + 0) * 10 + o] + bf2f(h0.y) * aux[(kb + 1) * 10 + o]
               + bf2f(h0.z) * aux[(kb + 2) * 10 + o] + bf2f(h0.w) * aux[(kb + 3) * 10 + o]
               + bf2f(h1.x) * aux[(kb + 4) * 10 + o] + bf2f(h1.y) * aux[(kb + 5) * 10 + o]
               + bf2f(h1.z) * aux[(kb + 6) * 10 + o] + bf2f(h1.w) * aux[(kb + 7) * 10 + o];
        }
        out[(size_t)(b0 + m) * 10 + o] = s;
    }
}

// ============================================================================
// fp32 prep: D[u,v] = EPI(sum_k A[k][u]*B[k][v]) batched over 8
// ============================================================================
template<int EPI>
__launch_bounds__(256)
__global__ void gemm256b(float* __restrict__ D, const float* __restrict__ A,
                         const float* __restrict__ Bm, const float* __restrict__ E)
{
    __shared__ float As[16][64];
    __shared__ float Bs[16][64];
    const int i = blockIdx.z;
    const size_t off = (size_t)i * 65536;
    const float* Ai = A + off;
    const float* Bi = Bm + off;
    const int t  = threadIdx.x;
    const int tx = t & 15, ty = t >> 4;
    const int u0 = blockIdx.y * 64, v0 = blockIdx.x * 64;
    const int lk = t >> 4, lv = (t & 15) << 2;

    float acc[4][4];
#pragma unroll
    for (int m = 0; m < 4; ++m)
#pragma unroll
        for (int n = 0; n < 4; ++n) acc[m][n] = 0.f;

    for (int k0 = 0; k0 < 256; k0 += 16) {
        __syncthreads();
        *(float4*)&As[lk][lv] = *(const float4*)(Ai + (size_t)(k0 + lk) * 256 + u0 + lv);
        *(float4*)&Bs[lk][lv] = *(const float4*)(Bi + (size_t)(k0 + lk) * 256 + v0 + lv);
        __syncthreads();
#pragma unroll
        for (int kk = 0; kk < 16; ++kk) {
            float af[4], bf[4];
            *(float4*)&af[0] = *(const float4*)&As[kk][ty * 4];
            *(float4*)&bf[0] = *(const float4*)&Bs[kk][tx * 4];
#pragma unroll
            for (int m = 0; m < 4; ++m)
#pragma unroll
                for (int n = 0; n < 4; ++n) acc[m][n] += af[m] * bf[n];
        }
    }

#pragma unroll
    for (int m = 0; m < 4; ++m) {
        const int u = u0 + ty * 4 + m;
        const size_t idx = off + (size_t)u * 256 + v0 + tx * 4;
        float4 r; float* rf = &r.x;
        if (EPI == 0) {
#pragma unroll
            for (int n = 0; n < 4; ++n) rf[n] = acc[m][n];
        } else if (EPI == 1) {
#pragma unroll
            for (int n = 0; n < 4; ++n)
                rf[n] = acc[m][n] + ((u == v0 + tx * 4 + n) ? 2.f : 0.f);
        } else {
            float4 e = *(const float4*)&E[idx];
            const float* ef = &e.x;
#pragma unroll
            for (int n = 0; n < 4; ++n) rf[n] = 2.f * ef[n] - acc[m][n];
        }
        *(float4*)&D[idx] = r;
    }
}

// transpose (Bt[k][u] = B0[u][k]) + bq = 0.1 * B0^T q : 1 launch
__launch_bounds__(256)
__global__ void prep_bt_bq(const float* __restrict__ B0, const float* __restrict__ q,
                           float* __restrict__ Bt, float* __restrict__ bq)
{
    __shared__ float tl[32][33];
    __shared__ float qs[256];
    const int i = blockIdx.x;
    const float* S = B0 + (size_t)i * 65536;
    float* D = Bt + (size_t)i * 65536;
    const int t = threadIdx.x;
    const int tx = t & 31, ty = t >> 5;   // 32 x 8
    for (int tile = 0; tile < 64; ++tile) {
        const int u0 = (tile >> 3) * 32, k0 = (tile & 7) * 32;
        __syncthreads();
#pragma unroll
        for (int r = 0; r < 32; r += 8)
            tl[ty + r][tx] = S[(size_t)(u0 + ty + r) * 256 + k0 + tx];
        __syncthreads();
#pragma unroll
        for (int r = 0; r < 32; r += 8)
            D[(size_t)(k0 + ty + r) * 256 + u0 + tx] = tl[tx][ty + r];
    }
    __syncthreads();
    qs[t] = q[i * 256 + t];
    __syncthreads();
    float s = 0.f;
    for (int k = 0; k < 256; ++k) s += S[(size_t)k * 256 + t] * qs[k];
    bq[i * 256 + t] = 0.1f * s;
}

// alpha = ||C||_inf, then quadratic NS seed X0 = a I + b C (rho0 ~ 0.1)
__launch_bounds__(256)
__global__ void prep_alpha_seed(const float* __restrict__ C, float* __restrict__ X)
{
    __shared__ float red[256];
    const int i = blockIdx.x;
    const int t = threadIdx.x;
    float s = 0.f;
    for (int v = 0; v < 256; ++v) s += fabsf(C[(size_t)i * 65536 + (size_t)v * 256 + t]);
    red[t] = s;
    __syncthreads();
    for (int off = 128; off > 0; off >>= 1) {
        if (t < off) red[t] = fmaxf(red[t], red[t + off]);
        __syncthreads();
    }
    const float bt = red[0];                       // >= lambda_max; lambda_min >= 2
    const float r = (2.f + bt) * (2.f + bt) / (8.f * bt);
    const float e = (r - 1.f) / (r + 1.f);
    const float b = -(1.f - e) / (2.f * bt);
    const float a = -b * (2.f + bt);
    for (int idx = t; idx < 65536; idx += 256) {
        const int r_ = idx >> 8, c_ = idx & 255;
        X[(size_t)i * 65536 + idx] = b * C[(size_t)i * 65536 + idx] + ((r_ == c_) ? a : 0.f);
    }
}

// c1 = M bq (odd cc slots), then c0 = 0.1 q - B c1 (even slots) : 1 launch
__launch_bounds__(256)
__global__ void prep_cc(const float* __restrict__ M, const float* __restrict__ Bt,
                        const float* __restrict__ bq, const float* __restrict__ q,
                        float* __restrict__ cc)
{
    __shared__ float vs[256];
    __shared__ float c1s[256];
    const int i = blockIdx.x;
    const int u = threadIdx.x;
    vs[u] = bq[i * 256 + u];
    __syncthreads();
    float s = 0.f;
    for (int k = 0; k < 256; ++k) s += M[(size_t)i * 65536 + (size_t)k * 256 + u] * vs[k];
    c1s[u] = s;
    cc[i * 512 + 2 * u + 1] = s;
    __syncthreads();
    float s2 = 0.f;
    for (int k = 0; k < 256; ++k) s2 += Bt[(size_t)i * 65536 + (size_t)k * 256 + u] * c1s[k];
    cc[i * 512 + 2 * u] = 0.1f * q[i * 256 + u] - s2;
}

// Wc[i][c][1024] hi|lo pack (interleaved z0/z1 columns)
__launch_bounds__(256)
__global__ void pack_wcomb(const float* __restrict__ P, const float* __restrict__ R,
                           const float* __restrict__ M, u16* __restrict__ W)
{
    const int i = blockIdx.y;
    const int e = blockIdx.x * 256 + threadIdx.x;   // 0..262143
    const int c = e >> 9, k = e & 511;
    const int u = c >> 1, parity = c & 1;
    const size_t off = (size_t)i * 65536;
    float v;
    if (parity == 0) {
        if (k < 256) v = ((u == k) ? 1.f : 0.f) - R[off + (size_t)u * 256 + k];
        else         v = -P[off + (size_t)(k - 256) * 256 + u];
    } else {
        if (k < 256) v = P[off + (size_t)u * 256 + k];
        else         v = M[off + (size_t)u * 256 + (k - 256)];
    }
    u16 h, l; fsplit(v, h, l);
    const size_t o = (size_t)i * 524288 + (size_t)c * 1024 + k;
    W[o] = h; W[o + 512] = l;
}

// W_in [784][256] -> Wi[256 u][1600] hi|lo (transposed, zero-padded)
__global__ void pack_win(const float* __restrict__ Wsrc, u16* __restrict__ W)
{
    int k = blockIdx.x * 256 + threadIdx.x;
    int u = blockIdx.y;
    if (k >= 800) return;
    float v = (k < 784) ? Wsrc[(size_t)k * 256 + u] : 0.f;
    u16 h, l; fsplit(v, h, l);
    W[(size_t)u * 1600 + k] = h;
    W[(size_t)u * 1600 + 800 + k] = l;
}

extern "C" void kernel_launch(void* const* d_in, const int* in_sizes, int n_in,
                              void* d_out, int out_size, void* d_ws, size_t ws_size,
                              hipStream_t stream)
{
    const float* x     = (const float*)d_in[0];
    const float* W_in  = (const float*)d_in[1];
    const float* b_in  = (const float*)d_in[2];
    const float* B0    = (const float*)d_in[3];
    const float* q     = (const float*)d_in[4];
    const float* W_out = (const float*)d_in[5];
    const float* b_out = (const float*)d_in[6];

    u16* Wc = (u16*)d_ws;                  // 8 * 524288 u16 = 8 MB
    u16* Wi = Wc + 8 * 524288;             // 256*1600
    float* bq = (float*)(Wi + 409600);
    float* cc = bq + 2048;                 // 8*512
    float* F  = cc + 4096;                 // prep scratch: 7 * 524288 floats
    float* Bt = F;
    float* C  = F + 1 * 524288;
    float* X  = F + 2 * 524288;
    float* X2 = F + 3 * 524288;
    float* Y  = F + 4 * 524288;
    float* P  = F + 5 * 524288;
    float* R  = F + 6 * 524288;

    // ---- per-layer matrix prep (fp32) ----
    prep_bt_bq<<<8, 256, 0, stream>>>(B0, q, Bt, bq);
    gemm256b<1><<<dim3(4, 4, 8), 256, 0, stream>>>(C, B0, B0, nullptr); // C = B^T B + 2I
    prep_alpha_seed<<<8, 256, 0, stream>>>(C, X);
    float* Xc = X; float* Xn = X2;
    for (int it = 0; it < 3; ++it) {   // Newton-Schulz: X <- 2X - X C X
        gemm256b<0><<<dim3(4, 4, 8), 256, 0, stream>>>(Y, C, Xc, nullptr);
        gemm256b<2><<<dim3(4, 4, 8), 256, 0, stream>>>(Xn, Xc, Y, Xc);
        float* tmp = Xc; Xc = Xn; Xn = tmp;
    }
    // Xc = M = (B^T B + 2I)^{-1} (symmetric)
    gemm256b<0><<<dim3(4, 4, 8), 256, 0, stream>>>(P, Xc, Bt, nullptr);  // P = M B^T
    gemm256b<0><<<dim3(4, 4, 8), 256, 0, stream>>>(R, Bt, P, nullptr);   // R = B P
    prep_cc<<<8, 256, 0, stream>>>(Xc, Bt, bq, q, cc);

    // ---- weight packs ----
    pack_wcomb<<<dim3(1024, 8), 256, 0, stream>>>(P, R, Xc, Wc);
    pack_win<<<dim3(4, 256), 256, 0, stream>>>(W_in, Wi);

    // ---- the whole network in one kernel ----
    meganet<<<BATCH_N / 64, 512, 0, stream>>>(
        x, Wi, b_in, Wc, cc, W_out, b_out, (float*)d_out);
}